// Round 7
// baseline (7064.633 us; speedup 1.0000x reference)
//
#include <hip/hip_runtime.h>
#include <hip/hip_cooperative_groups.h>
#include <stdint.h>

namespace cg = cooperative_groups;

#define NPTS     262144
#define HALF     131072
#define DIM      64
#define NCLUST   256
#define NTHREADS 512
#define NBLOCKS  256

// ---------------- JAX threefry2x32 (20 rounds) ----------------
__device__ __forceinline__ uint32_t rotl(uint32_t x, uint32_t r){ return (x<<r)|(x>>(32u-r)); }

__device__ __forceinline__ void tf(uint32_t k0, uint32_t k1, uint32_t x0, uint32_t x1,
                                   uint32_t &o0, uint32_t &o1){
  const uint32_t k2 = k0 ^ k1 ^ 0x1BD11BDAu;
  x0 += k0; x1 += k1;
#define RR(r) { x0 += x1; x1 = rotl(x1, r); x1 ^= x0; }
  RR(13u) RR(15u) RR(26u) RR(6u)   x0 += k1; x1 += k2 + 1u;
  RR(17u) RR(29u) RR(16u) RR(24u)  x0 += k2; x1 += k0 + 2u;
  RR(13u) RR(15u) RR(26u) RR(6u)   x0 += k0; x1 += k1 + 3u;
  RR(17u) RR(29u) RR(16u) RR(24u)  x0 += k1; x1 += k2 + 4u;
  RR(13u) RR(15u) RR(26u) RR(6u)   x0 += k2; x1 += k0 + 5u;
#undef RR
  o0 = x0; o1 = x1;
}

// partitionable random_bits (bit_width=32): bits[j] = o0 ^ o1 of tf(key, (0, j))
__device__ __forceinline__ uint32_t tf_xor(uint32_t k0, uint32_t k1, uint32_t j){
  uint32_t o0, o1; tf(k0, k1, 0u, j, o0, o1); return o0 ^ o1;
}

// JAX uniform(minval=tiny, maxval=1): u = bitcast((bits>>9)|0x3F800000)-1; u += tiny; max(tiny,u)
__device__ __forceinline__ float jax_uniform(uint32_t bits){
  const float tiny = 1.17549435e-38f;
  float u = __uint_as_float((bits >> 9) | 0x3F800000u) - 1.0f;
  u = u + tiny;
  u = fmaxf(tiny, u);
  return u;
}

// sortable packing: max(packed) == (max score, min index) like jnp.argmax tie-break
__device__ __forceinline__ unsigned long long packScore(float s, uint32_t j){
  uint32_t b = __float_as_uint(s);
  uint32_t m = (b & 0x80000000u) ? ~b : (b | 0x80000000u);
  return ((unsigned long long)m << 32) | (unsigned long long)(0x3FFFFu - j);
}

__global__ __launch_bounds__(NTHREADS, 1)
void kmpp_kernel(const float* __restrict__ buf, float* __restrict__ out,
                 unsigned long long* __restrict__ slots, int nslot){
  cg::grid_group grid = cg::this_grid();
  const int tid  = threadIdx.x;
  const int bid  = blockIdx.x;
  const int lane = tid & 63;
  const int wv   = tid >> 6;
  // thread owns points j0 (low half) and j1 = j0 + HALF
  const uint32_t j0 = (uint32_t)(bid * NTHREADS + tid);
  const uint32_t j1 = j0 + (uint32_t)HALF;

  __shared__ __align__(16) float cL[DIM];
  __shared__ uint32_t rk0[NCLUST], rk1[NCLUST];
  __shared__ unsigned long long wmax[NTHREADS/64];
  __shared__ int sIdx;

  // precompute round keys: fold_in(key(42), i) = tf((0,42), (0,i))
  for(int i = tid; i < NCLUST; i += NTHREADS){
    uint32_t a, b; tf(0u, 42u, 0u, (uint32_t)i, a, b);
    rk0[i] = a; rk1[i] = b;
  }
  __syncthreads();

  // ---- idx0 = randint(fold_in(key,0), (), 0, n) ----
  // split (fold-like): k2 = tf(k_fold0, (0,1)); lower_bits = o0^o1 of tf(k2,(0,0));
  // span = 2^18 -> multiplier term vanishes -> idx0 = lower_bits & 0x3FFFF
  uint32_t s0k, s1k, u0, u1;
  tf(rk0[0], rk1[0], 0u, 1u, s0k, s1k);
  tf(s0k, s1k, 0u, 0u, u0, u1);
  const uint32_t idx0 = (u0 ^ u1) & (uint32_t)(NPTS - 1);

  // ---- persistent per-thread data: 2 points in registers ----
  float x0[DIM], x1[DIM];
#pragma unroll
  for(int d=0; d<DIM; d+=4){
    float4 v0 = *reinterpret_cast<const float4*>(buf + (size_t)j0*DIM + d);
    float4 v1 = *reinterpret_cast<const float4*>(buf + (size_t)j1*DIM + d);
    x0[d]=v0.x; x0[d+1]=v0.y; x0[d+2]=v0.z; x0[d+3]=v0.w;
    x1[d]=v1.x; x1[d+1]=v1.y; x1[d+2]=v1.z; x1[d+3]=v1.w;
  }

  if(tid < DIM){
    float v = buf[(size_t)idx0*DIM + tid];
    cL[tid] = v;
    if(bid == 0) out[tid] = v;      // centroid row 0
  }
  __syncthreads();

  float m0 = 0.f, m1 = 0.f;
#pragma unroll
  for(int d=0; d<DIM; d+=4){
    float4 c4 = *reinterpret_cast<const float4*>(cL + d);
    float t;
    t = x0[d  ]-c4.x; m0 += t*t;  t = x1[d  ]-c4.x; m1 += t*t;
    t = x0[d+1]-c4.y; m0 += t*t;  t = x1[d+1]-c4.y; m1 += t*t;
    t = x0[d+2]-c4.z; m0 += t*t;  t = x1[d+2]-c4.z; m1 += t*t;
    t = x0[d+3]-c4.w; m0 += t*t;  t = x1[d+3]-c4.w; m1 += t*t;
  }
  __syncthreads();

  for(int i=1; i<NCLUST; i++){
    // gumbel bits for my two points, iteration key = fold_in(key, i) (from LDS)
    const uint32_t f0 = rk0[i], f1 = rk1[i];
    uint32_t t0 = tf_xor(f0, f1, j0);
    uint32_t t1 = tf_xor(f0, f1, j1);
    float g0 = -logf(-logf(jax_uniform(t0)));
    float g1 = -logf(-logf(jax_uniform(t1)));
    float s0 = g0 + logf(m0);
    float s1 = g1 + logf(m1);
    unsigned long long p0 = packScore(s0, j0);
    unsigned long long p1 = packScore(s1, j1);
    unsigned long long p = p0 > p1 ? p0 : p1;
#pragma unroll
    for(int off=32; off; off>>=1){
      unsigned long long q = __shfl_xor(p, off, 64);
      if(q > p) p = q;
    }
    if(lane == 0) wmax[wv] = p;
    __syncthreads();
    if(wv == 0){
      unsigned long long q = (lane < NTHREADS/64) ? wmax[lane] : 0ull;
#pragma unroll
      for(int off=4; off; off>>=1){
        unsigned long long r = __shfl_xor(q, off, 64);
        if(r > q) q = r;
      }
      if(lane == 0)
        atomicMax(&slots[(size_t)i*nslot + (bid & (nslot-1))], q);
    }
    grid.sync();

    // every block reduces the nslot shard maxima -> same winner everywhere
    if(wv == 0){
      unsigned long long q = 0ull;
      if(lane < nslot)
        q = __hip_atomic_load(&slots[(size_t)i*nslot + lane],
                              __ATOMIC_RELAXED, __HIP_MEMORY_SCOPE_AGENT);
#pragma unroll
      for(int off=32; off; off>>=1){
        unsigned long long r = __shfl_xor(q, off, 64);
        if(r > q) q = r;
      }
      if(lane == 0) sIdx = (int)(0x3FFFFu - (uint32_t)(q & 0xFFFFFFFFull));
    }
    __syncthreads();
    const int widx = sIdx;

    if(tid < DIM){
      float v = buf[(size_t)widx*DIM + tid];
      cL[tid] = v;
      if(bid == 0) out[(size_t)i*DIM + tid] = v;   // centroid row i
    }
    __syncthreads();

    if(i < NCLUST-1){
      float a0f = 0.f, a1f = 0.f;
#pragma unroll
      for(int d=0; d<DIM; d+=4){
        float4 c4 = *reinterpret_cast<const float4*>(cL + d);
        float t;
        t = x0[d  ]-c4.x; a0f += t*t;  t = x1[d  ]-c4.x; a1f += t*t;
        t = x0[d+1]-c4.y; a0f += t*t;  t = x1[d+1]-c4.y; a1f += t*t;
        t = x0[d+2]-c4.z; a0f += t*t;  t = x1[d+2]-c4.z; a1f += t*t;
        t = x0[d+3]-c4.w; a0f += t*t;  t = x1[d+3]-c4.w; a1f += t*t;
      }
      m0 = fminf(m0, a0f);
      m1 = fminf(m1, a1f);
    }
    __syncthreads();
  }
}

extern "C" void kernel_launch(void* const* d_in, const int* in_sizes, int n_in,
                              void* d_out, int out_size, void* d_ws, size_t ws_size,
                              hipStream_t stream){
  const float* buf = (const float*)d_in[0];
  float* out = (float*)d_out;
  unsigned long long* slots = (unsigned long long*)d_ws;

  int nslot = 64;
  while(nslot > 1 && (size_t)NCLUST * (size_t)nslot * sizeof(unsigned long long) > ws_size)
    nslot >>= 1;

  hipMemsetAsync(d_ws, 0, (size_t)NCLUST * (size_t)nslot * sizeof(unsigned long long), stream);

  dim3 g(NBLOCKS), b(NTHREADS);
  void* args[] = { (void*)&buf, (void*)&out, (void*)&slots, (void*)&nslot };
  hipLaunchCooperativeKernel((void*)kmpp_kernel, g, b, args, 0, stream);
}

// Round 12
// 2294.056 us; speedup vs baseline: 3.0795x; 3.0795x over previous
//
#include <hip/hip_runtime.h>
#include <stdint.h>

#define NPTS     262144
#define HALF     131072
#define DIM      64
#define NCLUST   256
#define NTHREADS 512
#define NBLOCKS  256

// ---------------- JAX threefry2x32 (20 rounds) ----------------
__device__ __forceinline__ uint32_t rotl(uint32_t x, uint32_t r){ return (x<<r)|(x>>(32u-r)); }

__device__ __forceinline__ void tf(uint32_t k0, uint32_t k1, uint32_t x0, uint32_t x1,
                                   uint32_t &o0, uint32_t &o1){
  const uint32_t k2 = k0 ^ k1 ^ 0x1BD11BDAu;
  x0 += k0; x1 += k1;
#define RR(r) { x0 += x1; x1 = rotl(x1, r); x1 ^= x0; }
  RR(13u) RR(15u) RR(26u) RR(6u)   x0 += k1; x1 += k2 + 1u;
  RR(17u) RR(29u) RR(16u) RR(24u)  x0 += k2; x1 += k0 + 2u;
  RR(13u) RR(15u) RR(26u) RR(6u)   x0 += k0; x1 += k1 + 3u;
  RR(17u) RR(29u) RR(16u) RR(24u)  x0 += k1; x1 += k2 + 4u;
  RR(13u) RR(15u) RR(26u) RR(6u)   x0 += k2; x1 += k0 + 5u;
#undef RR
  o0 = x0; o1 = x1;
}

// partitionable random_bits (bit_width=32): bits[j] = o0 ^ o1 of tf(key, (0, j))
__device__ __forceinline__ uint32_t tf_xor(uint32_t k0, uint32_t k1, uint32_t j){
  uint32_t o0, o1; tf(k0, k1, 0u, j, o0, o1); return o0 ^ o1;
}

// JAX uniform(minval=tiny, maxval=1)
__device__ __forceinline__ float jax_uniform(uint32_t bits){
  const float tiny = 1.17549435e-38f;
  float u = __uint_as_float((bits >> 9) | 0x3F800000u) - 1.0f;
  u = u + tiny;
  u = fmaxf(tiny, u);
  return u;
}

__device__ __forceinline__ float gumbel(uint32_t bits){
  return -logf(-logf(jax_uniform(bits)));
}

// sortable packing: max(packed) == (max score, min index); provably nonzero
// (high word m==0 would require s == negative NaN, impossible here)
__device__ __forceinline__ unsigned long long packScore(float s, uint32_t j){
  uint32_t b = __float_as_uint(s);
  uint32_t m = (b & 0x80000000u) ? ~b : (b | 0x80000000u);
  return ((unsigned long long)m << 32) | (unsigned long long)(0x3FFFFu - j);
}

__device__ __forceinline__ unsigned long long umax64(unsigned long long a, unsigned long long b){
  return a > b ? a : b;
}

__global__ __launch_bounds__(NTHREADS, 1)
void kmpp_kernel(const float* __restrict__ buf, float* __restrict__ out,
                 unsigned long long* __restrict__ slotsA,
                 unsigned long long* __restrict__ slotsB,
                 unsigned int* __restrict__ cntB,
                 int modeA){
  const int tid  = threadIdx.x;
  const int bid  = blockIdx.x;
  const int lane = tid & 63;
  const int wv   = tid >> 6;
  const uint32_t j0 = (uint32_t)(bid * NTHREADS + tid);
  const uint32_t j1 = j0 + (uint32_t)HALF;

  __shared__ __align__(16) float cL[DIM];
  __shared__ uint32_t rk0[NCLUST], rk1[NCLUST];
  __shared__ unsigned long long wmax[NTHREADS/64];
  __shared__ int sIdx;

  // round keys: fold_in(key(42), i) = tf((0,42), (0,i))
  for(int i = tid; i < NCLUST; i += NTHREADS){
    uint32_t a, b; tf(0u, 42u, 0u, (uint32_t)i, a, b);
    rk0[i] = a; rk1[i] = b;
  }
  __syncthreads();

  // idx0 = randint(fold_in(key,0), (), 0, n): foldlike split -> keys[1]; bits = o0^o1
  uint32_t s0k, s1k, u0, u1;
  tf(rk0[0], rk1[0], 0u, 1u, s0k, s1k);
  tf(s0k, s1k, 0u, 0u, u0, u1);
  const uint32_t idx0 = (u0 ^ u1) & (uint32_t)(NPTS - 1);

  // persistent per-thread points (register/AGPR resident)
  float x0[DIM], x1[DIM];
#pragma unroll
  for(int d=0; d<DIM; d+=4){
    float4 v0 = *reinterpret_cast<const float4*>(buf + (size_t)j0*DIM + d);
    float4 v1 = *reinterpret_cast<const float4*>(buf + (size_t)j1*DIM + d);
    x0[d]=v0.x; x0[d+1]=v0.y; x0[d+2]=v0.z; x0[d+3]=v0.w;
    x1[d]=v1.x; x1[d+1]=v1.y; x1[d+2]=v1.z; x1[d+3]=v1.w;
  }

  if(tid < DIM){
    float v = buf[(size_t)idx0*DIM + tid];
    cL[tid] = v;
    if(bid == 0) out[tid] = v;
  }
  __syncthreads();

  float m0 = 0.f, m1 = 0.f;
#pragma unroll
  for(int d=0; d<DIM; d+=4){
    float4 c4 = *reinterpret_cast<const float4*>(cL + d);
    float t;
    t = x0[d  ]-c4.x; m0 += t*t;  t = x1[d  ]-c4.x; m1 += t*t;
    t = x0[d+1]-c4.y; m0 += t*t;  t = x1[d+1]-c4.y; m1 += t*t;
    t = x0[d+2]-c4.z; m0 += t*t;  t = x1[d+2]-c4.z; m1 += t*t;
    t = x0[d+3]-c4.w; m0 += t*t;  t = x1[d+3]-c4.w; m1 += t*t;
  }

  // precompute round-1 gumbels (independent of min_d)
  float g0 = gumbel(tf_xor(rk0[1], rk1[1], j0));
  float g1 = gumbel(tf_xor(rk0[1], rk1[1], j1));

  for(int i=1; i<NCLUST; i++){
    float s0 = g0 + logf(m0);
    float s1 = g1 + logf(m1);
    unsigned long long p = umax64(packScore(s0, j0), packScore(s1, j1));
#pragma unroll
    for(int off=32; off; off>>=1)
      p = umax64(p, __shfl_xor(p, off, 64));
    if(lane == 0) wmax[wv] = p;

    // precompute NEXT round's gumbels while other waves finish (hides 2 tf + 2 log)
    if(i < NCLUST-1){
      g0 = gumbel(tf_xor(rk0[i+1], rk1[i+1], j0));
      g1 = gumbel(tf_xor(rk0[i+1], rk1[i+1], j1));
    }
    __syncthreads();                     // wmax ready

    if(wv == 0){
      // block max from 8 wave maxima
      unsigned long long bq = (lane < NTHREADS/64) ? wmax[lane] : 0ull;
#pragma unroll
      for(int off=4; off; off>>=1)
        bq = umax64(bq, __shfl_xor(bq, off, 64));

      unsigned long long q;
      if(modeA){
        // publish block max: per-round per-block slot, release store
        if(lane == 0)
          __hip_atomic_store(&slotsA[((size_t)i<<8) + bid], bq,
                             __ATOMIC_RELEASE, __HIP_MEMORY_SCOPE_AGENT);
        // poll all 256 slots (4 per lane) until nonzero
        const size_t base = ((size_t)i<<8) + (size_t)(lane*4);
        unsigned long long v0,v1,v2,v3;
        int iter = 0;
        for(;;){
          v0 = __hip_atomic_load(&slotsA[base+0], __ATOMIC_RELAXED, __HIP_MEMORY_SCOPE_AGENT);
          v1 = __hip_atomic_load(&slotsA[base+1], __ATOMIC_RELAXED, __HIP_MEMORY_SCOPE_AGENT);
          v2 = __hip_atomic_load(&slotsA[base+2], __ATOMIC_RELAXED, __HIP_MEMORY_SCOPE_AGENT);
          v3 = __hip_atomic_load(&slotsA[base+3], __ATOMIC_RELAXED, __HIP_MEMORY_SCOPE_AGENT);
          bool ok = (v0 != 0ull) && (v1 != 0ull) && (v2 != 0ull) && (v3 != 0ull);
          if(__all(ok) || ++iter > 4000000) break;
          __builtin_amdgcn_s_sleep(1);
        }
        q = umax64(umax64(v0,v1), umax64(v2,v3));
      } else {
        // fallback: shared atomicMax slots + arrival counter
        if(lane == 0){
          atomicMax(&slotsB[(size_t)i*64 + (bid & 63)], bq);
          __hip_atomic_fetch_add(&cntB[i], 1u, __ATOMIC_RELEASE, __HIP_MEMORY_SCOPE_AGENT);
          int iter = 0;
          while(__hip_atomic_load(&cntB[i], __ATOMIC_ACQUIRE, __HIP_MEMORY_SCOPE_AGENT) < NBLOCKS
                && ++iter <= 4000000)
            __builtin_amdgcn_s_sleep(1);
        }
        __threadfence();
        q = __hip_atomic_load(&slotsB[(size_t)i*64 + lane], __ATOMIC_RELAXED,
                              __HIP_MEMORY_SCOPE_AGENT);
      }
#pragma unroll
      for(int off=32; off; off>>=1)
        q = umax64(q, __shfl_xor(q, off, 64));
      if(lane == 0) sIdx = (int)(0x3FFFFu - (uint32_t)(q & 0xFFFFFFFFull));
    }
    __syncthreads();                     // sIdx ready
    const int widx = sIdx;

    if(tid < DIM){
      float v = buf[(size_t)widx*DIM + tid];
      cL[tid] = v;
      if(bid == 0) out[(size_t)i*DIM + tid] = v;
    }
    __syncthreads();                     // cL ready

    if(i < NCLUST-1){
      float a0f = 0.f, a1f = 0.f;
#pragma unroll
      for(int d=0; d<DIM; d+=4){
        float4 c4 = *reinterpret_cast<const float4*>(cL + d);
        float t;
        t = x0[d  ]-c4.x; a0f += t*t;  t = x1[d  ]-c4.x; a1f += t*t;
        t = x0[d+1]-c4.y; a0f += t*t;  t = x1[d+1]-c4.y; a1f += t*t;
        t = x0[d+2]-c4.z; a0f += t*t;  t = x1[d+2]-c4.z; a1f += t*t;
        t = x0[d+3]-c4.w; a0f += t*t;  t = x1[d+3]-c4.w; a1f += t*t;
      }
      m0 = fminf(m0, a0f);
      m1 = fminf(m1, a1f);
    }
  }
}

extern "C" void kernel_launch(void* const* d_in, const int* in_sizes, int n_in,
                              void* d_out, int out_size, void* d_ws, size_t ws_size,
                              hipStream_t stream){
  const float* buf = (const float*)d_in[0];
  float* out = (float*)d_out;

  const size_t szA = (size_t)NCLUST * NBLOCKS * sizeof(unsigned long long);   // 512 KiB
  const size_t szB = (size_t)NCLUST * 64 * sizeof(unsigned long long)
                   + (size_t)NCLUST * sizeof(unsigned int);                   // 129 KiB
  int modeA = (ws_size >= szA) ? 1 : 0;

  unsigned long long* slotsA = (unsigned long long*)d_ws;
  unsigned long long* slotsB = (unsigned long long*)d_ws;
  unsigned int* cntB = (unsigned int*)((char*)d_ws + (size_t)NCLUST * 64 * sizeof(unsigned long long));

  hipMemsetAsync(d_ws, 0, modeA ? szA : szB, stream);

  dim3 g(NBLOCKS), b(NTHREADS);
  void* args[] = { (void*)&buf, (void*)&out, (void*)&slotsA, (void*)&slotsB,
                   (void*)&cntB, (void*)&modeA };
  hipLaunchCooperativeKernel((void*)kmpp_kernel, g, b, args, 0, stream);
}